// Round 10
// baseline (38.793 us; speedup 1.0000x reference)
//
#include <hip/hip_runtime.h>

#define NB 8
#define NT 1024
#define NK 8
#define NL 1024
#define NH 256
#define NE 128
#define NF 64
#define NV 23

typedef __attribute__((ext_vector_type(8))) short bf16x8;
typedef __attribute__((ext_vector_type(4))) float f32x4;

__device__ __forceinline__ unsigned cvt_pk_bf16(float lo, float hi) {
  unsigned r;
  asm("v_cvt_pk_bf16_f32 %0, %1, %2" : "=v"(r) : "v"(lo), "v"(hi));
  return r;
}

__device__ __forceinline__ uint4 pack8(const float4 f0, const float4 f1) {
  uint4 u;
  u.x = cvt_pk_bf16(f0.x, f0.y);
  u.y = cvt_pk_bf16(f0.z, f0.w);
  u.z = cvt_pk_bf16(f1.x, f1.y);
  u.w = cvt_pk_bf16(f1.z, f1.w);
  return u;
}

// ---------------------------------------------------------------------------
// Prep: two pre-swizzled bf16 images of W1 slices (chunk = 8 k x 1 n, 16 B).
//  imgEx (4096 chunks): g in [0,16)  -> W1 rows 256+g*8..+7   (ex slice)
//  imgB (10240 chunks): g in [0,32)  -> W1 rows g*8..+7       (hs slice)
//                       g in [32,40) -> W1 rows 384+(g-32)*8  (col slice)
//  chunk address: g*256 + (n ^ (g&7)).
// ---------------------------------------------------------------------------
__global__ __launch_bounds__(256) void k_prep(const float* __restrict__ W1,
                                              uint4* __restrict__ imgEx,
                                              uint4* __restrict__ imgB) {
  const int c = blockIdx.x * 256 + threadIdx.x;  // 3584 slots of 4 chunks
  int g, n0, wrow0;
  uint4* img;
  if (c < 1024) {
    g = c >> 6; n0 = (c & 63) * 4;
    wrow0 = NH + g * 8;
    img = imgEx;
  } else {
    const int c2 = c - 1024;
    g = c2 >> 6; n0 = (c2 & 63) * 4;
    wrow0 = (g < 32) ? g * 8 : 384 + (g - 32) * 8;
    img = imgB;
  }
  float4 r[8];
#pragma unroll
  for (int j = 0; j < 8; ++j)
    r[j] = *(const float4*)&W1[(size_t)(wrow0 + j) * NH + n0];
  const float* rf = (const float*)r;
#pragma unroll
  for (int d = 0; d < 4; ++d) {
    uint4 u;
    u.x = cvt_pk_bf16(rf[0 * 4 + d], rf[1 * 4 + d]);
    u.y = cvt_pk_bf16(rf[2 * 4 + d], rf[3 * 4 + d]);
    u.z = cvt_pk_bf16(rf[4 * 4 + d], rf[5 * 4 + d]);
    u.w = cvt_pk_bf16(rf[6 * 4 + d], rf[7 * 4 + d]);
    img[g * 256 + ((n0 + d) ^ (g & 7))] = u;
  }
}

// ---------------------------------------------------------------------------
// Mega kernel, small-block max-TLP variant:
//  block = 256 threads (4 waves), 8 t rows x 8 k = 64 ex rows; grid 1024.
//  b = bid&7 (XCD-affine), t0 = (bid>>3)*8.
//  LDS: ONLY Ub (16 KB) -> with VGPR<=128: 4 blocks/CU, 16 waves, 4
//  independent phase schedules per CU. No global_load_lds, ONE barrier.
//  ex B-fragments are read straight from global imgEx (L2/L1-hot).
//   1) base: M=16 frag (rows lm&7; lm>=8 are L1-hit duplicates), 4 n-frags
//      per wave (full N=256 across 4 waves), B from imgB -> Ub (lm<8)
//   2) lane-private ex gather + pack
//   3) barrier
//   4) ex MFMA: 2 half-N passes, acc[8], B from GLOBAL imgEx; fold
//      relu(acc+Ub).W2 per half
//   5) shfl reduce + softmax(k) + lambda/p_copy stores
// ---------------------------------------------------------------------------
__global__ __launch_bounds__(256, 4) void k_mega(
    const float* __restrict__ hs, const float* __restrict__ ex,
    const float* __restrict__ col, const int* __restrict__ c_t,
    const int* __restrict__ aa_ids, const uint4* __restrict__ imgEx,
    const uint4* __restrict__ imgB, const float* __restrict__ b1,
    const float* __restrict__ W2, const float* __restrict__ b2,
    float* __restrict__ p_copy, float* __restrict__ lam) {
  extern __shared__ uint4 smem[];
  uint4* Ub = smem;  // 16 rows x 64 chunks = 16 KB; phys slot = s ^ row

  const int tid = threadIdx.x;
  const int lane = tid & 63;
  const int w = tid >> 6;    // 0..3
  const int lm = lane & 15;
  const int lg = lane >> 4;
  const int bid = blockIdx.x;
  const int b = bid & 7;             // XCD-affine
  const int t0 = (bid >> 3) * 8;

  const int t_local = w * 2 + (lm >> 3);          // 0..7
  const int t = t0 + t_local;
  const int ctv = c_t[b * NT + t];
  const bool valid = ctv >= 0;
  const int c = valid ? ctv : 0;

  // ---- phase 1: base part, M=16 (8 real t rows), 4 n-frags/wave ----
  {
    const int myt = t0 + (lm & 7);
    const int ctv2 = c_t[b * NT + myt];
    const int myc = ctv2 < 0 ? 0 : ctv2;
    f32x4 accB[4];
#pragma unroll
    for (int f = 0; f < 4; ++f) {
      const float4 bv = *(const float4*)&b1[(w * 4 + f) * 16 + lg * 4];
      accB[f][0] = bv.x; accB[f][1] = bv.y; accB[f][2] = bv.z; accB[f][3] = bv.w;
    }
#pragma unroll
    for (int ks = 0; ks < 10; ++ks) {
      const int gk = ks * 4 + lg;  // 0..39
      const float* asrc = (gk < 32)
          ? &hs[((size_t)b * NT + myt) * NH + gk * 8]
          : &col[((size_t)b * NL + myc) * NF + (gk - 32) * 8];
      const float4 f0 = *(const float4*)asrc;
      const float4 f1 = *(const float4*)(asrc + 4);
      union { uint4 u; bf16x8 v; } A;
      A.u = pack8(f0, f1);
#pragma unroll
      for (int f = 0; f < 4; ++f) {
        const int n = (w * 4 + f) * 16 + lm;
        union { uint4 u; bf16x8 v; } B2;
        B2.u = imgB[(size_t)gk * 256 + (n ^ (gk & 7))];
        accB[f] = __builtin_amdgcn_mfma_f32_16x16x32_bf16(B2.v, A.v, accB[f], 0, 0, 0);
      }
    }
    // deposit rows 0..7 only (lm>=8 computed duplicates)
    if (lm < 8) {
#pragma unroll
      for (int f = 0; f < 4; ++f) {
        union { uint4 u; f32x4 v; } o;
        o.v = accB[f];
        Ub[lm * 64 + (((w * 4 + f) * 4 + lg) ^ lm)] = o.u;
      }
    }
  }

  // ---- phase 2: lane-private ex gather (k = lm&7, col c of its t) ----
  const float* arow = &ex[(((size_t)b * NK + (lm & 7)) * NL + c) * NE];
  uint4 aPk[4];
  {
    float4 pf[8];
#pragma unroll
    for (int ks = 0; ks < 4; ++ks) {
      const int g = ks * 4 + lg;
      pf[2 * ks] = *(const float4*)(arow + g * 8);
      pf[2 * ks + 1] = *(const float4*)(arow + g * 8 + 4);
    }
#pragma unroll
    for (int ks = 0; ks < 4; ++ks) aPk[ks] = pack8(pf[2 * ks], pf[2 * ks + 1]);
  }

  __syncthreads();

  // ---- phase 4: two half-N passes, B straight from global imgEx ----
  const float b2v = b2[0];
  float p = 0.f;
#pragma unroll 1
  for (int half = 0; half < 2; ++half) {
    f32x4 acc[8] = {};
#pragma unroll
    for (int ks = 0; ks < 4; ++ks) {
      const int g = ks * 4 + lg;
      union { uint4 u; bf16x8 v; } A;
      A.u = aPk[ks];
#pragma unroll
      for (int fn = 0; fn < 8; ++fn) {
        const int n = half * 128 + fn * 16 + lm;
        union { uint4 u; bf16x8 v; } B2;
        B2.u = imgEx[(size_t)g * 256 + (n ^ (g & 7))];
        acc[fn] = __builtin_amdgcn_mfma_f32_16x16x32_bf16(B2.v, A.v, acc[fn], 0, 0, 0);
      }
    }
#pragma unroll
    for (int fn = 0; fn < 8; ++fn) {
      const int n0 = half * 128 + fn * 16 + lg * 4;
      union { uint4 u; f32x4 v; } ubv;
      ubv.u = Ub[t_local * 64 + ((half * 32 + fn * 4 + lg) ^ t_local)];
      const float4 w2v = *(const float4*)&W2[n0];
      p += fmaxf(acc[fn][0] + ubv.v[0], 0.f) * w2v.x +
           fmaxf(acc[fn][1] + ubv.v[1], 0.f) * w2v.y +
           fmaxf(acc[fn][2] + ubv.v[2], 0.f) * w2v.z +
           fmaxf(acc[fn][3] + ubv.v[3], 0.f) * w2v.w;
    }
  }
  p += __shfl_xor(p, 16);
  p += __shfl_xor(p, 32);
  const float score = p + b2v;

  float mx = score;
  mx = fmaxf(mx, __shfl_xor(mx, 1));
  mx = fmaxf(mx, __shfl_xor(mx, 2));
  mx = fmaxf(mx, __shfl_xor(mx, 4));
  const float e = __expf(score - mx);
  float s = e;
  s += __shfl_xor(s, 1);
  s += __shfl_xor(s, 2);
  s += __shfl_xor(s, 4);
  const float wgt = valid ? (e / s) : 0.f;

  // lambda: lg==0 lanes cover 2 t rows x 8 k = 16 consecutive floats
  if (lg == 0) lam[((size_t)b * NT + t0 + w * 2) * NK + lm] = wgt;

  int aav = 0;
  if (lg == 0) aav = aa_ids[((size_t)b * NK + (lm & 7)) * NL + c];

  const int bin = lane & 31;
  const int half = lane >> 5;
  const int src0 = half * 8;
  float pc = 0.f;
#pragma unroll
  for (int k = 0; k < 8; ++k) {
    const int a = __shfl(aav, src0 + k);
    const float ww = __shfl(wgt, src0 + k);
    pc += (a == bin) ? ww : 0.f;
  }
  if (bin < NV)
    p_copy[((size_t)b * NT + t0 + w * 2 + half) * NV + bin] = pc;
}

extern "C" void kernel_launch(void* const* d_in, const int* in_sizes, int n_in,
                              void* d_out, int out_size, void* d_ws, size_t ws_size,
                              hipStream_t stream) {
  const float* hs = (const float*)d_in[0];
  const float* ex = (const float*)d_in[1];
  const float* col = (const float*)d_in[2];
  const int* ct = (const int*)d_in[3];
  const int* aa = (const int*)d_in[4];
  const float* W1 = (const float*)d_in[5];
  const float* b1 = (const float*)d_in[6];
  const float* W2 = (const float*)d_in[7];
  const float* b2 = (const float*)d_in[8];

  uint4* imgEx = (uint4*)d_ws;        // 64 KB
  uint4* imgB = imgEx + 4096;         // 160 KB

  float* p_copy = (float*)d_out;
  float* lam = p_copy + (size_t)NB * NT * NV;

  const size_t lds_bytes = 1024 * sizeof(uint4);  // 16 KB (Ub only)

  k_prep<<<14, 256, 0, stream>>>(W1, imgEx, imgB);
  k_mega<<<1024, 256, lds_bytes, stream>>>(hs, ex, col, ct, aa, imgEx, imgB,
                                           b1, W2, b2, p_copy, lam);
}

// Round 12
// 35.150 us; speedup vs baseline: 1.1036x; 1.1036x over previous
//
#include <hip/hip_runtime.h>

#define NB 8
#define NT 1024
#define NK 8
#define NL 1024
#define NH 256
#define NE 128
#define NF 64
#define NV 23

typedef __attribute__((ext_vector_type(8))) short bf16x8;
typedef __attribute__((ext_vector_type(4))) float f32x4;

__device__ __forceinline__ unsigned cvt_pk_bf16(float lo, float hi) {
  unsigned r;
  asm("v_cvt_pk_bf16_f32 %0, %1, %2" : "=v"(r) : "v"(lo), "v"(hi));
  return r;
}

__device__ __forceinline__ uint4 pack8(const float4 f0, const float4 f1) {
  uint4 u;
  u.x = cvt_pk_bf16(f0.x, f0.y);
  u.y = cvt_pk_bf16(f0.z, f0.w);
  u.z = cvt_pk_bf16(f1.x, f1.y);
  u.w = cvt_pk_bf16(f1.z, f1.w);
  return u;
}

// ---------------------------------------------------------------------------
// k_pre: blocks 0..13 = W1 image prep (R9-verified); blocks 14.. = ex
// transpose+convert: ex (b,k,l,e) f32 -> exT (b,l,k,e) bf16, so one (b,t)
// gather in mega becomes ONE contiguous 2 KB block instead of 8 random 512 B
// rows, and gathered bytes halve.
//  imgEx (4096 chunks): g in [0,16)  -> W1 rows 256+g*8..+7   (ex slice)
//  imgB (10240 chunks): g in [0,32)  -> W1 rows g*8..+7       (hs slice)
//                       g in [32,40) -> W1 rows 384+(g-32)*8  (col slice)
//  chunk address: g*256 + (n ^ (g&7)).
// ---------------------------------------------------------------------------
__global__ __launch_bounds__(256) void k_pre(const float* __restrict__ W1,
                                             const float* __restrict__ ex,
                                             uint4* __restrict__ imgEx,
                                             uint4* __restrict__ imgB,
                                             unsigned short* __restrict__ exT) {
  const int bid = blockIdx.x;
  if (bid < 14) {
    const int c = bid * 256 + threadIdx.x;  // 3584 slots of 4 chunks
    int g, n0, wrow0;
    uint4* img;
    if (c < 1024) {
      g = c >> 6; n0 = (c & 63) * 4;
      wrow0 = NH + g * 8;
      img = imgEx;
    } else {
      const int c2 = c - 1024;
      g = c2 >> 6; n0 = (c2 & 63) * 4;
      wrow0 = (g < 32) ? g * 8 : 384 + (g - 32) * 8;
      img = imgB;
    }
    float4 r[8];
#pragma unroll
    for (int j = 0; j < 8; ++j)
      r[j] = *(const float4*)&W1[(size_t)(wrow0 + j) * NH + n0];
    const float* rf = (const float*)r;
#pragma unroll
    for (int d = 0; d < 4; ++d) {
      uint4 u;
      u.x = cvt_pk_bf16(rf[0 * 4 + d], rf[1 * 4 + d]);
      u.y = cvt_pk_bf16(rf[2 * 4 + d], rf[3 * 4 + d]);
      u.z = cvt_pk_bf16(rf[4 * 4 + d], rf[5 * 4 + d]);
      u.w = cvt_pk_bf16(rf[6 * 4 + d], rf[7 * 4 + d]);
      img[g * 256 + ((n0 + d) ^ (g & 7))] = u;
    }
  } else {
    // transpose block: 4 l's of one b; thread = (k = tid>>5, e0 = (tid&31)*4)
    const int tb = bid - 14;           // 0..2047
    const int b = tb >> 8;
    const int l0 = (tb & 255) * 4;
    const int k = threadIdx.x >> 5;
    const int e0 = (threadIdx.x & 31) * 4;
#pragma unroll
    for (int i = 0; i < 4; ++i) {
      const int l = l0 + i;
      const float4 v =
          *(const float4*)&ex[(((size_t)b * NK + k) * NL + l) * NE + e0];
      uint2 o;
      o.x = cvt_pk_bf16(v.x, v.y);
      o.y = cvt_pk_bf16(v.z, v.w);
      *(uint2*)&exT[(((size_t)b * NL + l) * NK + k) * NE + e0] = o;
    }
  }
}

// ---------------------------------------------------------------------------
// Mega kernel (R9-verified structure): block = (b, 16 t rows), 8 waves,
// LDS = 80 KB (Bs 64 + Ub 16) -> 2 blocks/CU. b = bid&7 (XCD-affine).
//   issue base-hb0 loads -> issue global_load_lds staging (8/wave) ->
//   base hb0 compute -> base hb1 -> Ub write -> ex A-frags DIRECT bf16 from
//   exT (contiguous 2 KB per (b,c), no pack) -> barrier ->
//   two half-N MFMA passes (acc[8]) with relu.W2 dot folded in ->
//   shfl reduce -> softmax(k) -> lambda/p_copy stores.
// ---------------------------------------------------------------------------
__global__ __launch_bounds__(512, 4) void k_mega(
    const float* __restrict__ hs, const unsigned short* __restrict__ exT,
    const float* __restrict__ col, const int* __restrict__ c_t,
    const int* __restrict__ aa_ids, const uint4* __restrict__ imgEx,
    const uint4* __restrict__ imgB, const float* __restrict__ b1,
    const float* __restrict__ W2, const float* __restrict__ b2,
    float* __restrict__ p_copy, float* __restrict__ lam) {
  extern __shared__ uint4 smem[];
  uint4* Bs = smem;          // 4096 chunks = 64 KB
  uint4* Ub = smem + 4096;   // 1024 chunks = 16 KB: t*64 + (slot ^ t)

  const int tid = threadIdx.x;
  const int lane = tid & 63;
  const int w = tid >> 6;    // 0..7
  const int lm = lane & 15;
  const int lg = lane >> 4;
  const int bid = blockIdx.x;
  const int b = bid & 7;             // XCD-affine
  const int t0 = (bid >> 3) * 16;

  const int t_local = w * 2 + (lm >> 3);
  const int t = t0 + t_local;
  const int ctv = c_t[b * NT + t];
  const bool valid = ctv >= 0;
  const int c = valid ? ctv : 0;

  const int myt = t0 + lm;
  const int ctv2 = c_t[b * NT + myt];
  const int myc = ctv2 < 0 ? 0 : ctv2;

  f32x4 accB[2];
#pragma unroll
  for (int f = 0; f < 2; ++f) {
    const float4 bv = *(const float4*)&b1[(w * 2 + f) * 16 + lg * 4];
    accB[f][0] = bv.x; accB[f][1] = bv.y; accB[f][2] = bv.z; accB[f][3] = bv.w;
  }

  // ---- base hb0: issue loads FIRST (older than staging in vmcnt FIFO) ----
  float4 f0a[5], f1a[5];
  uint4 bb[10];
#pragma unroll
  for (int i = 0; i < 5; ++i) {
    const int gk = i * 4 + lg;  // 0..19
    const float* asrc = &hs[((size_t)b * NT + myt) * NH + gk * 8];
    f0a[i] = *(const float4*)asrc;
    f1a[i] = *(const float4*)(asrc + 4);
  }
#pragma unroll
  for (int i = 0; i < 5; ++i) {
    const int gk = i * 4 + lg;
#pragma unroll
    for (int f = 0; f < 2; ++f) {
      const int n = (w * 2 + f) * 16 + lm;
      bb[i * 2 + f] = imgB[(size_t)gk * 256 + (n ^ (gk & 7))];
    }
  }

  // ---- staging: issue global_load_lds (stays in flight under base) ----
#pragma unroll
  for (int it = 0; it < 8; ++it) {
    const int off = (w * 8 + it) * 64;
    __builtin_amdgcn_global_load_lds(
        (const __attribute__((address_space(1))) void*)(imgEx + off + lane),
        (__attribute__((address_space(3))) void*)(Bs + off), 16, 0, 0);
  }

  // ---- base hb0 compute ----
#pragma unroll
  for (int i = 0; i < 5; ++i) {
    union { uint4 u; bf16x8 v; } A;
    A.u = pack8(f0a[i], f1a[i]);
#pragma unroll
    for (int f = 0; f < 2; ++f) {
      union { uint4 u; bf16x8 v; } B2;
      B2.u = bb[i * 2 + f];
      accB[f] = __builtin_amdgcn_mfma_f32_16x16x32_bf16(B2.v, A.v, accB[f], 0, 0, 0);
    }
  }

  // ---- base hb1: loads + compute ----
#pragma unroll
  for (int i = 0; i < 5; ++i) {
    const int gk = 20 + i * 4 + lg;  // 20..39
    const float* asrc = (gk < 32)
        ? &hs[((size_t)b * NT + myt) * NH + gk * 8]
        : &col[((size_t)b * NL + myc) * NF + (gk - 32) * 8];
    f0a[i] = *(const float4*)asrc;
    f1a[i] = *(const float4*)(asrc + 4);
  }
#pragma unroll
  for (int i = 0; i < 5; ++i) {
    const int gk = 20 + i * 4 + lg;
#pragma unroll
    for (int f = 0; f < 2; ++f) {
      const int n = (w * 2 + f) * 16 + lm;
      bb[i * 2 + f] = imgB[(size_t)gk * 256 + (n ^ (gk & 7))];
    }
  }
#pragma unroll
  for (int i = 0; i < 5; ++i) {
    union { uint4 u; bf16x8 v; } A;
    A.u = pack8(f0a[i], f1a[i]);
#pragma unroll
    for (int f = 0; f < 2; ++f) {
      union { uint4 u; bf16x8 v; } B2;
      B2.u = bb[i * 2 + f];
      accB[f] = __builtin_amdgcn_mfma_f32_16x16x32_bf16(B2.v, A.v, accB[f], 0, 0, 0);
    }
  }

  // ---- Ub deposit: row lm, slot s = (w*2+f)*4+lg, phys = s ^ lm ----
#pragma unroll
  for (int f = 0; f < 2; ++f) {
    union { uint4 u; f32x4 v; } o;
    o.v = accB[f];
    Ub[lm * 64 + (((w * 2 + f) * 4 + lg) ^ lm)] = o.u;
  }

  // ---- ex A-frags: direct bf16 loads from exT (contiguous per (b,c)) ----
  const unsigned short* arow =
      &exT[(((size_t)b * NL + c) * NK + (lm & 7)) * NE];
  uint4 aPk[4];
#pragma unroll
  for (int ks = 0; ks < 4; ++ks) {
    const int g = ks * 4 + lg;
    aPk[ks] = *(const uint4*)(arow + g * 8);
  }

  __syncthreads();

  // ---- phase 4: two sequential half-N passes, partial dot folded in ----
  const float b2v = b2[0];
  float p = 0.f;
#pragma unroll 1
  for (int half = 0; half < 2; ++half) {
    f32x4 acc[8] = {};
#pragma unroll
    for (int ks = 0; ks < 4; ++ks) {
      const int g = ks * 4 + lg;
      union { uint4 u; bf16x8 v; } A;
      A.u = aPk[ks];
#pragma unroll
      for (int fn = 0; fn < 8; ++fn) {
        const int n = half * 128 + fn * 16 + lm;
        const bf16x8 bfr = *(const bf16x8*)&Bs[g * 256 + (n ^ (g & 7))];
        acc[fn] = __builtin_amdgcn_mfma_f32_16x16x32_bf16(bfr, A.v, acc[fn], 0, 0, 0);
      }
    }
#pragma unroll
    for (int fn = 0; fn < 8; ++fn) {
      const int n0 = half * 128 + fn * 16 + lg * 4;
      union { uint4 u; f32x4 v; } ubv;
      ubv.u = Ub[t_local * 64 + ((half * 32 + fn * 4 + lg) ^ t_local)];
      const float4 w2v = *(const float4*)&W2[n0];
      p += fmaxf(acc[fn][0] + ubv.v[0], 0.f) * w2v.x +
           fmaxf(acc[fn][1] + ubv.v[1], 0.f) * w2v.y +
           fmaxf(acc[fn][2] + ubv.v[2], 0.f) * w2v.z +
           fmaxf(acc[fn][3] + ubv.v[3], 0.f) * w2v.w;
    }
  }
  p += __shfl_xor(p, 16);
  p += __shfl_xor(p, 32);
  const float score = p + b2v;

  float mx = score;
  mx = fmaxf(mx, __shfl_xor(mx, 1));
  mx = fmaxf(mx, __shfl_xor(mx, 2));
  mx = fmaxf(mx, __shfl_xor(mx, 4));
  const float e = __expf(score - mx);
  float s = e;
  s += __shfl_xor(s, 1);
  s += __shfl_xor(s, 2);
  s += __shfl_xor(s, 4);
  const float wgt = valid ? (e / s) : 0.f;

  if (lg == 0) lam[((size_t)b * NT + t0 + w * 2) * NK + lm] = wgt;

  int aav = 0;
  if (lg == 0) aav = aa_ids[((size_t)b * NK + (lm & 7)) * NL + c];

  const int bin = lane & 31;
  const int half = lane >> 5;
  const int src0 = half * 8;
  float pc = 0.f;
#pragma unroll
  for (int k = 0; k < 8; ++k) {
    const int a = __shfl(aav, src0 + k);
    const float ww = __shfl(wgt, src0 + k);
    pc += (a == bin) ? ww : 0.f;
  }
  if (bin < NV)
    p_copy[((size_t)b * NT + t0 + w * 2 + half) * NV + bin] = pc;
}

extern "C" void kernel_launch(void* const* d_in, const int* in_sizes, int n_in,
                              void* d_out, int out_size, void* d_ws, size_t ws_size,
                              hipStream_t stream) {
  const float* hs = (const float*)d_in[0];
  const float* ex = (const float*)d_in[1];
  const float* col = (const float*)d_in[2];
  const int* ct = (const int*)d_in[3];
  const int* aa = (const int*)d_in[4];
  const float* W1 = (const float*)d_in[5];
  const float* b1 = (const float*)d_in[6];
  const float* W2 = (const float*)d_in[7];
  const float* b2 = (const float*)d_in[8];

  uint4* imgEx = (uint4*)d_ws;                              // 64 KB
  uint4* imgB = imgEx + 4096;                               // 160 KB
  unsigned short* exT = (unsigned short*)(imgB + 10240);    // 16.8 MB bf16

  float* p_copy = (float*)d_out;
  float* lam = p_copy + (size_t)NB * NT * NV;

  const size_t lds_bytes = (4096 + 1024) * sizeof(uint4);  // 80 KB

  k_pre<<<14 + 2048, 256, 0, stream>>>(W1, ex, imgEx, imgB, exT);
  k_mega<<<512, 512, lds_bytes, stream>>>(hs, exT, col, ct, aa, imgEx, imgB,
                                          b1, W2, b2, p_copy, lam);
}

// Round 13
// 26.695 us; speedup vs baseline: 1.4532x; 1.3167x over previous
//
#include <hip/hip_runtime.h>

#define NB 8
#define NT 1024
#define NK 8
#define NL 1024
#define NH 256
#define NE 128
#define NF 64
#define NV 23

typedef __attribute__((ext_vector_type(8))) short bf16x8;
typedef __attribute__((ext_vector_type(4))) float f32x4;

__device__ __forceinline__ unsigned cvt_pk_bf16(float lo, float hi) {
  unsigned r;
  asm("v_cvt_pk_bf16_f32 %0, %1, %2" : "=v"(r) : "v"(lo), "v"(hi));
  return r;
}

__device__ __forceinline__ uint4 pack8(const float4 f0, const float4 f1) {
  uint4 u;
  u.x = cvt_pk_bf16(f0.x, f0.y);
  u.y = cvt_pk_bf16(f0.z, f0.w);
  u.z = cvt_pk_bf16(f1.x, f1.y);
  u.w = cvt_pk_bf16(f1.z, f1.w);
  return u;
}

// ---------------------------------------------------------------------------
// Prep: two pre-swizzled bf16 images of W1 slices (chunk = 8 k x 1 n, 16 B).
//  imgEx (4096 chunks): g in [0,16)  -> W1 rows 256+g*8..+7   (ex slice)
//  imgB (10240 chunks): g in [0,32)  -> W1 rows g*8..+7       (hs slice)
//                       g in [32,40) -> W1 rows 384+(g-32)*8  (col slice)
//  chunk address: g*256 + (n ^ (g&7)).
// ---------------------------------------------------------------------------
__global__ __launch_bounds__(256) void k_prep(const float* __restrict__ W1,
                                              uint4* __restrict__ imgEx,
                                              uint4* __restrict__ imgB) {
  const int c = blockIdx.x * 256 + threadIdx.x;  // 3584 slots of 4 chunks
  int g, n0, wrow0;
  uint4* img;
  if (c < 1024) {
    g = c >> 6; n0 = (c & 63) * 4;
    wrow0 = NH + g * 8;
    img = imgEx;
  } else {
    const int c2 = c - 1024;
    g = c2 >> 6; n0 = (c2 & 63) * 4;
    wrow0 = (g < 32) ? g * 8 : 384 + (g - 32) * 8;
    img = imgB;
  }
  float4 r[8];
#pragma unroll
  for (int j = 0; j < 8; ++j)
    r[j] = *(const float4*)&W1[(size_t)(wrow0 + j) * NH + n0];
  const float* rf = (const float*)r;
#pragma unroll
  for (int d = 0; d < 4; ++d) {
    uint4 u;
    u.x = cvt_pk_bf16(rf[0 * 4 + d], rf[1 * 4 + d]);
    u.y = cvt_pk_bf16(rf[2 * 4 + d], rf[3 * 4 + d]);
    u.z = cvt_pk_bf16(rf[4 * 4 + d], rf[5 * 4 + d]);
    u.w = cvt_pk_bf16(rf[6 * 4 + d], rf[7 * 4 + d]);
    img[g * 256 + ((n0 + d) ^ (g & 7))] = u;
  }
}

// ---------------------------------------------------------------------------
// Mega kernel, fully-coalesced staging variant.
// Block = (b, 16 t rows), 8 waves (512 thr), LDS = 122 KB -> 1 block/CU.
// All global A-traffic is cooperatively COALESCED (no 64-way scattered
// lane-private loads):
//   stage issue: hs (16 rows x 1 KB, 32B/lane runs), col (16 rows x 256 B),
//   ex gather (128 rows x 512 B runs, R4 pattern) -> reg; THEN Bs DMA
//   (youngest in vmcnt FIFO); pack f32->bf16; ds_write XOR-swizzled.
//   barrier 1
//   base: A-frags from hsS/colS LDS, B from L1-hot imgB; Ub -> LDS.
//   aPk from exS.
//   barrier 2
//   phase 4: two half-N MFMA passes (acc[8]) + relu.W2 fold (R9 verbatim),
//   shfl reduce, softmax(k), lambda/p_copy stores.
// ---------------------------------------------------------------------------
__global__ __launch_bounds__(512, 2) void k_mega(
    const float* __restrict__ hs, const float* __restrict__ ex,
    const float* __restrict__ col, const int* __restrict__ c_t,
    const int* __restrict__ aa_ids, const uint4* __restrict__ imgEx,
    const uint4* __restrict__ imgB, const float* __restrict__ b1,
    const float* __restrict__ W2, const float* __restrict__ b2,
    float* __restrict__ p_copy, float* __restrict__ lam) {
  extern __shared__ uint4 smem[];
  uint4* Bs = smem;           // 4096 chunks = 64 KB  (W1ex image)
  uint4* exS = smem + 4096;   // 2048 chunks = 32 KB  g*128 + (m ^ (g&7))
  uint4* hsS = smem + 6144;   //  512 chunks =  8 KB  gk*16 + (row ^ (gk&7))
  uint4* colS = smem + 6656;  //  128 chunks =  2 KB  gc*16 + (row ^ (gc&7))
  uint4* Ub = smem + 6784;    // 1024 chunks = 16 KB  row*64 + (slot ^ row)

  const int tid = threadIdx.x;
  const int lane = tid & 63;
  const int w = tid >> 6;    // 0..7
  const int lm = lane & 15;
  const int lg = lane >> 4;
  const int bid = blockIdx.x;
  const int b = bid & 7;             // XCD-affine
  const int t0 = (bid >> 3) * 16;

  const int t_local = w * 2 + (lm >> 3);
  const int t = t0 + t_local;
  const int ctv = c_t[b * NT + t];
  const bool valid = ctv >= 0;
  const int c = valid ? ctv : 0;

  // ---- stage issue: hs (row = tid>>5, gk = tid&31) ----
  const int srow = tid >> 5;
  const int sgk = tid & 31;
  const float* hsrc = &hs[((size_t)b * NT + t0 + srow) * NH + sgk * 8];
  const float4 h0 = *(const float4*)hsrc;
  const float4 h1 = *(const float4*)(hsrc + 4);

  // ---- stage issue: col (tid<128: row = tid>>3, gc = tid&7) ----
  float4 cf0, cf1;
  const int crow = tid >> 3;
  const int cgc = tid & 7;
  if (tid < 128) {
    const int cct = c_t[b * NT + t0 + crow];
    const int ccol = cct < 0 ? 0 : cct;
    const float* csrc = &col[((size_t)b * NL + ccol) * NF + cgc * 8];
    cf0 = *(const float4*)csrc;
    cf1 = *(const float4*)(csrc + 4);
  }

  // ---- stage issue: ex gather, coalesced (cc -> m = row, g = k-chunk) ----
  float4 e0[4], e1[4];
  int em[4], eg[4];
#pragma unroll
  for (int i = 0; i < 4; ++i) {
    const int cc = i * 512 + tid;  // 0..2047
    const int m = cc >> 4;         // 0..127 = tt*8 + k
    const int g = cc & 15;
    const int tt = m >> 3;
    const int k = m & 7;
    const int ct2 = c_t[b * NT + t0 + tt];
    const int c2 = ct2 < 0 ? 0 : ct2;
    const float* src = &ex[(((size_t)b * NK + k) * NL + c2) * NE + g * 8];
    e0[i] = *(const float4*)src;
    e1[i] = *(const float4*)(src + 4);
    em[i] = m;
    eg[i] = g;
  }

  // ---- Bs DMA (issued AFTER reg loads: youngest in vmcnt FIFO) ----
#pragma unroll
  for (int it = 0; it < 8; ++it) {
    const int off = (w * 8 + it) * 64;
    __builtin_amdgcn_global_load_lds(
        (const __attribute__((address_space(1))) void*)(imgEx + off + lane),
        (__attribute__((address_space(3))) void*)(Bs + off), 16, 0, 0);
  }

  // ---- pack + swizzled ds_write ----
  hsS[sgk * 16 + (srow ^ (sgk & 7))] = pack8(h0, h1);
  if (tid < 128) colS[cgc * 16 + (crow ^ (cgc & 7))] = pack8(cf0, cf1);
#pragma unroll
  for (int i = 0; i < 4; ++i)
    exS[eg[i] * 128 + (em[i] ^ (eg[i] & 7))] = pack8(e0[i], e1[i]);

  __syncthreads();  // barrier 1: staged LDS + DMA complete

  // ---- base: A from LDS, B from global imgB ----
  f32x4 accB[2];
#pragma unroll
  for (int f = 0; f < 2; ++f) {
    const float4 bv = *(const float4*)&b1[(w * 2 + f) * 16 + lg * 4];
    accB[f][0] = bv.x; accB[f][1] = bv.y; accB[f][2] = bv.z; accB[f][3] = bv.w;
  }
#pragma unroll
  for (int ks = 0; ks < 10; ++ks) {
    const int gk = ks * 4 + lg;  // 0..39
    union { uint4 u; bf16x8 v; } A;
    A.u = (gk < 32) ? hsS[gk * 16 + (lm ^ (gk & 7))]
                    : colS[(gk - 32) * 16 + (lm ^ ((gk - 32) & 7))];
#pragma unroll
    for (int f = 0; f < 2; ++f) {
      const int n = (w * 2 + f) * 16 + lm;
      union { uint4 u; bf16x8 v; } B2;
      B2.u = imgB[(size_t)gk * 256 + (n ^ (gk & 7))];
      accB[f] = __builtin_amdgcn_mfma_f32_16x16x32_bf16(B2.v, A.v, accB[f], 0, 0, 0);
    }
  }
#pragma unroll
  for (int f = 0; f < 2; ++f) {
    union { uint4 u; f32x4 v; } o;
    o.v = accB[f];
    Ub[lm * 64 + (((w * 2 + f) * 4 + lg) ^ lm)] = o.u;
  }

  // ---- phase-4 A-frags from exS (ready since barrier 1) ----
  uint4 aPk[4];
#pragma unroll
  for (int ks = 0; ks < 4; ++ks) {
    const int g = ks * 4 + lg;
    aPk[ks] = exS[g * 128 + ((w * 16 + lm) ^ (g & 7))];
  }

  __syncthreads();  // barrier 2: Ub visible

  // ---- phase 4: two sequential half-N passes, partial dot folded in ----
  const float b2v = b2[0];
  float p = 0.f;
#pragma unroll 1
  for (int half = 0; half < 2; ++half) {
    f32x4 acc[8] = {};
#pragma unroll
    for (int ks = 0; ks < 4; ++ks) {
      const int g = ks * 4 + lg;
      union { uint4 u; bf16x8 v; } A;
      A.u = aPk[ks];
#pragma unroll
      for (int fn = 0; fn < 8; ++fn) {
        const int n = half * 128 + fn * 16 + lm;
        const bf16x8 bfr = *(const bf16x8*)&Bs[g * 256 + (n ^ (g & 7))];
        acc[fn] = __builtin_amdgcn_mfma_f32_16x16x32_bf16(bfr, A.v, acc[fn], 0, 0, 0);
      }
    }
#pragma unroll
    for (int fn = 0; fn < 8; ++fn) {
      const int n0 = half * 128 + fn * 16 + lg * 4;
      union { uint4 u; f32x4 v; } ubv;
      ubv.u = Ub[t_local * 64 + ((half * 32 + fn * 4 + lg) ^ t_local)];
      const float4 w2v = *(const float4*)&W2[n0];
      p += fmaxf(acc[fn][0] + ubv.v[0], 0.f) * w2v.x +
           fmaxf(acc[fn][1] + ubv.v[1], 0.f) * w2v.y +
           fmaxf(acc[fn][2] + ubv.v[2], 0.f) * w2v.z +
           fmaxf(acc[fn][3] + ubv.v[3], 0.f) * w2v.w;
    }
  }
  p += __shfl_xor(p, 16);
  p += __shfl_xor(p, 32);
  const float score = p + b2v;

  float mx = score;
  mx = fmaxf(mx, __shfl_xor(mx, 1));
  mx = fmaxf(mx, __shfl_xor(mx, 2));
  mx = fmaxf(mx, __shfl_xor(mx, 4));
  const float e = __expf(score - mx);
  float s = e;
  s += __shfl_xor(s, 1);
  s += __shfl_xor(s, 2);
  s += __shfl_xor(s, 4);
  const float wgt = valid ? (e / s) : 0.f;

  if (lg == 0) lam[((size_t)b * NT + t0 + w * 2) * NK + lm] = wgt;

  int aav = 0;
  if (lg == 0) aav = aa_ids[((size_t)b * NK + (lm & 7)) * NL + c];

  const int bin = lane & 31;
  const int half = lane >> 5;
  const int src0 = half * 8;
  float pc = 0.f;
#pragma unroll
  for (int k = 0; k < 8; ++k) {
    const int a = __shfl(aav, src0 + k);
    const float ww = __shfl(wgt, src0 + k);
    pc += (a == bin) ? ww : 0.f;
  }
  if (bin < NV)
    p_copy[((size_t)b * NT + t0 + w * 2 + half) * NV + bin] = pc;
}

extern "C" void kernel_launch(void* const* d_in, const int* in_sizes, int n_in,
                              void* d_out, int out_size, void* d_ws, size_t ws_size,
                              hipStream_t stream) {
  const float* hs = (const float*)d_in[0];
  const float* ex = (const float*)d_in[1];
  const float* col = (const float*)d_in[2];
  const int* ct = (const int*)d_in[3];
  const int* aa = (const int*)d_in[4];
  const float* W1 = (const float*)d_in[5];
  const float* b1 = (const float*)d_in[6];
  const float* W2 = (const float*)d_in[7];
  const float* b2 = (const float*)d_in[8];

  uint4* imgEx = (uint4*)d_ws;        // 64 KB
  uint4* imgB = imgEx + 4096;         // 160 KB

  float* p_copy = (float*)d_out;
  float* lam = p_copy + (size_t)NB * NT * NV;

  const size_t lds_bytes = 7808 * sizeof(uint4);  // 122 KB -> 1 block/CU

  k_prep<<<14, 256, 0, stream>>>(W1, imgEx, imgB);
  k_mega<<<512, 512, lds_bytes, stream>>>(hs, ex, col, ct, aa, imgEx, imgB,
                                          b1, W2, b2, p_copy, lam);
}